// Round 2
// baseline (410.192 us; speedup 1.0000x reference)
//
#include <hip/hip_runtime.h>

typedef __bf16 bf16_t;
typedef __attribute__((ext_vector_type(4))) __bf16 bf16x4;
typedef __attribute__((ext_vector_type(8))) __bf16 bf16x8;
typedef __attribute__((ext_vector_type(4))) float floatx4;

#define MFMA16(a, b, c) __builtin_amdgcn_mfma_f32_16x16x32_bf16((a), (b), (c), 0, 0, 0)

constexpr int TT = 128;   // sequence length
constexpr int CD = 384;   // n_emb
constexpr int HS = 64;    // head size
constexpr int BB = 1024;  // batch
constexpr int W_ELEMS = HS * CD;            // 24576 per projection
constexpr size_t QKV_ELEMS = (size_t)BB * TT * HS;  // 8388608 per tensor
constexpr int PS_STR = 136;                 // P row stride in LDS (bf16 elems)

// ---- pre-kernel: Wq,Wk,Wv fp32 -> bf16 into ws as [3][64][384] (order q,k,v) ----
__global__ void wconv_kernel(const float* __restrict__ wq, const float* __restrict__ wk,
                             const float* __restrict__ wv, bf16_t* __restrict__ out) {
    int i = blockIdx.x * 256 + threadIdx.x;
    if (i < W_ELEMS)            out[i] = (bf16_t)wq[i];
    else if (i < 2 * W_ELEMS)   out[i] = (bf16_t)wk[i - W_ELEMS];
    else if (i < 3 * W_ELEMS)   out[i] = (bf16_t)wv[i - 2 * W_ELEMS];
}

// ---- kernel A: qkv projection. 16 rows per wave, no LDS, high occupancy. ----
// q,k stored [row][64] bf16; v stored transposed [b][64][128] bf16.
__launch_bounds__(256, 4)
__global__ void qkv_kernel(const float* __restrict__ x, const bf16_t* __restrict__ wc,
                           bf16_t* __restrict__ q, bf16_t* __restrict__ k,
                           bf16_t* __restrict__ vt) {
    const int lane = threadIdx.x & 63;
    const int w    = threadIdx.x >> 6;
    const int l15  = lane & 15;
    const int g    = lane >> 4;
    const int row0 = blockIdx.x * 64 + w * 16;  // this wave's 16 rows (stays within one batch)
    const float* xr = x + (size_t)(row0 + l15) * CD;

    floatx4 accq[4], acck[4], accv[4];
#pragma unroll
    for (int nt = 0; nt < 4; ++nt) {
        accq[nt] = (floatx4)0.0f;
        acck[nt] = (floatx4)0.0f;
        accv[nt] = (floatx4)0.0f;
    }

    for (int kk = 0; kk < CD; kk += 32) {
        const int c = kk + 8 * g;
        float4 f0 = *(const float4*)(xr + c);
        float4 f1 = *(const float4*)(xr + c + 4);
        bf16x8 a;
        a[0] = (bf16_t)f0.x; a[1] = (bf16_t)f0.y; a[2] = (bf16_t)f0.z; a[3] = (bf16_t)f0.w;
        a[4] = (bf16_t)f1.x; a[5] = (bf16_t)f1.y; a[6] = (bf16_t)f1.z; a[7] = (bf16_t)f1.w;
#pragma unroll
        for (int nt = 0; nt < 4; ++nt) {
            const int h = 16 * nt + l15;
            bf16x8 bq = *(const bf16x8*)(wc + 0 * W_ELEMS + h * CD + c);
            bf16x8 bk = *(const bf16x8*)(wc + 1 * W_ELEMS + h * CD + c);
            bf16x8 bv = *(const bf16x8*)(wc + 2 * W_ELEMS + h * CD + c);
            accq[nt] = MFMA16(a, bq, accq[nt]);
            acck[nt] = MFMA16(a, bk, acck[nt]);
            accv[nt] = MFMA16(a, bv, accv[nt]);
        }
    }

    // C/D layout: col = l15 (h within tile), row = 4*g + r (t within 16-row tile)
    const int b  = row0 >> 7;
    const int tl = (row0 & 127) + 4 * g;  // local t of r=0
#pragma unroll
    for (int nt = 0; nt < 4; ++nt) {
        const int h = 16 * nt + l15;
#pragma unroll
        for (int r = 0; r < 4; ++r) {
            const size_t rowg = (size_t)(row0 + 4 * g + r);
            q[rowg * HS + h] = (bf16_t)accq[nt][r];
            k[rowg * HS + h] = (bf16_t)acck[nt][r];
        }
        bf16x4 pv;
        pv[0] = (bf16_t)accv[nt][0]; pv[1] = (bf16_t)accv[nt][1];
        pv[2] = (bf16_t)accv[nt][2]; pv[3] = (bf16_t)accv[nt][3];
        *(bf16x4*)(vt + (size_t)b * HS * TT + (size_t)h * TT + tl) = pv;
    }
}

// ---- kernel B: attention. One block per batch; LDS only for P; no barriers. ----
__launch_bounds__(256, 4)
__global__ void attn2_kernel(const bf16_t* __restrict__ q, const bf16_t* __restrict__ k,
                             const bf16_t* __restrict__ vt, float* __restrict__ out) {
    __shared__ __align__(16) bf16_t pbuf[TT * PS_STR];  // 34816 B -> 4 blocks/CU
    const int b    = blockIdx.x;
    const int lane = threadIdx.x & 63;
    const int w    = threadIdx.x >> 6;
    const int l15  = lane & 15;
    const int g    = lane >> 4;
    const size_t qb = (size_t)b * TT * HS;
    const float scale = 0.05103103630798287f;  // 384^-0.5

    // q A-fragments straight from global: A[m=t=l15][k=h=8g+j]
    bf16x8 aq[2][2];
#pragma unroll
    for (int mt = 0; mt < 2; ++mt)
#pragma unroll
        for (int kt = 0; kt < 2; ++kt)
            aq[mt][kt] = *(const bf16x8*)(q + qb + (size_t)(32 * w + 16 * mt + l15) * HS + 32 * kt + 8 * g);

    // S = q k^T per 16-row strip, softmax, P -> LDS (own rows only)
#pragma unroll
    for (int mt = 0; mt < 2; ++mt) {
        floatx4 sacc[8];
#pragma unroll
        for (int nt = 0; nt < 8; ++nt) sacc[nt] = (floatx4)0.0f;
        const int ntmax = 2 * w + mt;  // last s-tile with any s <= t (wave-uniform)
#pragma unroll
        for (int kt = 0; kt < 2; ++kt) {
            for (int nt = 0; nt <= ntmax; ++nt) {
                bf16x8 bk = *(const bf16x8*)(k + qb + (size_t)(16 * nt + l15) * HS + 32 * kt + 8 * g);
                sacc[nt] = MFMA16(aq[mt][kt], bk, sacc[nt]);
            }
        }
#pragma unroll
        for (int r = 0; r < 4; ++r) {
            const int t = 32 * w + 16 * mt + 4 * g + r;
            float vals[8];
            float vmax = -__builtin_inff();
#pragma unroll
            for (int nt = 0; nt < 8; ++nt) {
                const int s = 16 * nt + l15;
                float v = (nt <= ntmax && s <= t) ? sacc[nt][r] * scale : -__builtin_inff();
                vals[nt] = v;
                vmax = fmaxf(vmax, v);
            }
            vmax = fmaxf(vmax, __shfl_xor(vmax, 1));
            vmax = fmaxf(vmax, __shfl_xor(vmax, 2));
            vmax = fmaxf(vmax, __shfl_xor(vmax, 4));
            vmax = fmaxf(vmax, __shfl_xor(vmax, 8));
            float sum = 0.0f;
#pragma unroll
            for (int nt = 0; nt < 8; ++nt) {
                float e = __expf(vals[nt] - vmax);
                vals[nt] = e;
                sum += e;
            }
            sum += __shfl_xor(sum, 1);
            sum += __shfl_xor(sum, 2);
            sum += __shfl_xor(sum, 4);
            sum += __shfl_xor(sum, 8);
            const float inv = 1.0f / sum;
#pragma unroll
            for (int nt = 0; nt < 8; ++nt)
                pbuf[t * PS_STR + 16 * nt + l15] = (bf16_t)(vals[nt] * inv);
        }
    }
    // no __syncthreads: each wave reads back only the P rows it wrote

    // O = P v : A from LDS (own rows), B = vT fragments from global
    floatx4 oacc[2][4];
#pragma unroll
    for (int mt = 0; mt < 2; ++mt)
#pragma unroll
        for (int nt = 0; nt < 4; ++nt) oacc[mt][nt] = (floatx4)0.0f;

    for (int st = 0; st <= w; ++st) {  // s-chunks of 32; P rows past causal edge are 0
        const int ss = 32 * st + 8 * g;
        bf16x8 ap0 = *(const bf16x8*)(pbuf + (32 * w + l15) * PS_STR + ss);
        bf16x8 ap1 = *(const bf16x8*)(pbuf + (32 * w + 16 + l15) * PS_STR + ss);
#pragma unroll
        for (int nt = 0; nt < 4; ++nt) {
            bf16x8 bv = *(const bf16x8*)(vt + (size_t)b * HS * TT + (size_t)(16 * nt + l15) * TT + ss);
            oacc[0][nt] = MFMA16(ap0, bv, oacc[0][nt]);
            oacc[1][nt] = MFMA16(ap1, bv, oacc[1][nt]);
        }
    }

    float* ob = out + qb;
#pragma unroll
    for (int mt = 0; mt < 2; ++mt)
#pragma unroll
        for (int nt = 0; nt < 4; ++nt) {
            const int t0 = 32 * w + 16 * mt + 4 * g;
            const int h  = 16 * nt + l15;
#pragma unroll
            for (int r = 0; r < 4; ++r)
                ob[(size_t)(t0 + r) * HS + h] = oacc[mt][nt][r];
        }
}

extern "C" void kernel_launch(void* const* d_in, const int* in_sizes, int n_in,
                              void* d_out, int out_size, void* d_ws, size_t ws_size,
                              hipStream_t stream) {
    // setup_inputs order: x, Wk, Wq, Wv
    const float* x  = (const float*)d_in[0];
    const float* wk = (const float*)d_in[1];
    const float* wq = (const float*)d_in[2];
    const float* wv = (const float*)d_in[3];
    float* out = (float*)d_out;

    // ws layout: [Wqkv bf16: 73728][q: 8.39M][k: 8.39M][vT: 8.39M] -> ~48.2 MiB total
    bf16_t* wc = (bf16_t*)d_ws;
    bf16_t* q  = wc + 3 * W_ELEMS;
    bf16_t* k  = q + QKV_ELEMS;
    bf16_t* vt = k + QKV_ELEMS;

    wconv_kernel<<<(3 * W_ELEMS + 255) / 256, 256, 0, stream>>>(wq, wk, wv, wc);
    qkv_kernel<<<(BB * TT) / 64, 256, 0, stream>>>(x, wc, q, k, vt);
    attn2_kernel<<<BB, 256, 0, stream>>>(q, k, vt, out);
}

// Round 3
// 329.236 us; speedup vs baseline: 1.2459x; 1.2459x over previous
//
#include <hip/hip_runtime.h>

typedef __bf16 bf16_t;
typedef __attribute__((ext_vector_type(8))) __bf16 bf16x8;
typedef __attribute__((ext_vector_type(4))) float floatx4;

#define MFMA16(a, b, c) __builtin_amdgcn_mfma_f32_16x16x32_bf16((a), (b), (c), 0, 0, 0)

constexpr int TT = 128;   // sequence length
constexpr int CD = 384;   // n_emb
constexpr int HS = 64;    // head size
constexpr int BB = 1024;  // batch

// LDS layout (units: bf16 elements)
constexpr int QK_STR = 72;    // q/k rows [t][h], 64+8 pad; 16B-aligned rows, 2-way bank alias (free)
constexpr int VT_STR = 136;   // v^T rows [h][t] and P rows [t][s], 128+8 pad, 16B-aligned
constexpr int QS_OFF = 0;
constexpr int KS_OFF = TT * QK_STR;        // 9216
constexpr int VT_OFF = 2 * TT * QK_STR;    // 18432
constexpr int PS_OFF = 0;                  // P overlays q+k after they are dead (17408 <= 18432)
constexpr int SMEM_N = 2 * TT * QK_STR + HS * VT_STR;  // 27136 bf16 = 54272 B -> 2 blocks/CU

// ---- pre-kernel: Wq,Wk,Wv fp32 -> bf16 in FRAGMENT ORDER ----
// wf[((proj*12+kki)*4+nt)*512 + lane*8 + j] = W_proj[16*nt + (lane&15)][32*kki + 8*(lane>>4) + j]
// => a weight-fragment load in the main kernel is base + lane*16B: one coalesced 1KB read.
__global__ void wconv_kernel(const float* __restrict__ wq, const float* __restrict__ wk,
                             const float* __restrict__ wv, bf16_t* __restrict__ wf) {
    const int t = blockIdx.x * 256 + threadIdx.x;  // 0 .. 9215
    if (t >= 3 * 12 * 4 * 64) return;
    const int lane = t & 63;
    const int f    = t >> 6;        // (proj*12+kki)*4+nt
    const int nt   = f & 3;
    const int kki  = (f >> 2) % 12;
    const int proj = f / 48;
    const float* W = (proj == 0) ? wq : ((proj == 1) ? wk : wv);
    const int h = 16 * nt + (lane & 15);
    const int c = 32 * kki + 8 * (lane >> 4);
    const float* src = W + h * CD + c;
    bf16x8 o;
#pragma unroll
    for (int j = 0; j < 8; ++j) o[j] = (bf16_t)src[j];
    *(bf16x8*)(wf + (size_t)t * 8) = o;
}

// ---- fused attention head: one block per batch element, 4 waves, wave w owns rows [32w,32w+32) ----
__launch_bounds__(256, 2)
__global__ void attn_kernel(const float* __restrict__ x, const bf16_t* __restrict__ wf,
                            float* __restrict__ out) {
    __shared__ __align__(16) bf16_t smem[SMEM_N];
    const int b    = blockIdx.x;
    const int lane = threadIdx.x & 63;
    const int w    = threadIdx.x >> 6;  // wave id 0..3
    const int l15  = lane & 15;
    const int g    = lane >> 4;         // 16-lane group 0..3
    const float* xb = x + (size_t)b * TT * CD;
    const bf16_t* wfl = wf + (size_t)lane * 8;  // this lane's slot; frag f at wfl + f*512

    // ================= Phase 1: q,k,v projections (register-double-buffered K loop) =================
    floatx4 accq[2][4], acck[2][4], accv[2][4];
#pragma unroll
    for (int mt = 0; mt < 2; ++mt)
#pragma unroll
        for (int nt = 0; nt < 4; ++nt) {
            accq[mt][nt] = (floatx4)0.0f;
            acck[mt][nt] = (floatx4)0.0f;
            accv[mt][nt] = (floatx4)0.0f;
        }

    float4 xa0[2], xa1[2];   // current raw x (fp32; cvt deferred to use site)
    bf16x8 wb[12];           // current weight frags, [proj*4+nt]
#pragma unroll
    for (int mt = 0; mt < 2; ++mt) {
        const float* p = xb + (size_t)(32 * w + 16 * mt + l15) * CD + 8 * g;
        xa0[mt] = *(const float4*)p;
        xa1[mt] = *(const float4*)(p + 4);
    }
#pragma unroll
    for (int pn = 0; pn < 12; ++pn) {
        const int proj = pn >> 2, nt = pn & 3;
        wb[pn] = *(const bf16x8*)(wfl + (size_t)((proj * 12 + 0) * 4 + nt) * 512);
    }

#pragma unroll
    for (int kki = 0; kki < 12; ++kki) {
        float4 xn0[2], xn1[2];
        bf16x8 wn[12];
        if (kki < 11) {  // prefetch next iteration (pure loads, no dependent VALU)
            const int c = 32 * (kki + 1) + 8 * g;
#pragma unroll
            for (int mt = 0; mt < 2; ++mt) {
                const float* p = xb + (size_t)(32 * w + 16 * mt + l15) * CD + c;
                xn0[mt] = *(const float4*)p;
                xn1[mt] = *(const float4*)(p + 4);
            }
#pragma unroll
            for (int pn = 0; pn < 12; ++pn) {
                const int proj = pn >> 2, nt = pn & 3;
                wn[pn] = *(const bf16x8*)(wfl + (size_t)((proj * 12 + kki + 1) * 4 + nt) * 512);
            }
        }
        // convert current x to bf16 A-fragments
        bf16x8 a[2];
#pragma unroll
        for (int mt = 0; mt < 2; ++mt) {
            bf16x8 t;
            t[0] = (bf16_t)xa0[mt].x; t[1] = (bf16_t)xa0[mt].y;
            t[2] = (bf16_t)xa0[mt].z; t[3] = (bf16_t)xa0[mt].w;
            t[4] = (bf16_t)xa1[mt].x; t[5] = (bf16_t)xa1[mt].y;
            t[6] = (bf16_t)xa1[mt].z; t[7] = (bf16_t)xa1[mt].w;
            a[mt] = t;
        }
#pragma unroll
        for (int nt = 0; nt < 4; ++nt) {
            accq[0][nt] = MFMA16(a[0], wb[0 + nt], accq[0][nt]);
            accq[1][nt] = MFMA16(a[1], wb[0 + nt], accq[1][nt]);
            acck[0][nt] = MFMA16(a[0], wb[4 + nt], acck[0][nt]);
            acck[1][nt] = MFMA16(a[1], wb[4 + nt], acck[1][nt]);
            accv[0][nt] = MFMA16(a[0], wb[8 + nt], accv[0][nt]);
            accv[1][nt] = MFMA16(a[1], wb[8 + nt], accv[1][nt]);
        }
        if (kki < 11) {  // rotate (renamed away by unroll)
#pragma unroll
            for (int mt = 0; mt < 2; ++mt) { xa0[mt] = xn0[mt]; xa1[mt] = xn1[mt]; }
#pragma unroll
            for (int pn = 0; pn < 12; ++pn) wb[pn] = wn[pn];
        }
    }

    // Write q,k as [t][h]; v transposed as [h][t]. C/D layout: col=lane&15, row=4*g+reg.
#pragma unroll
    for (int mt = 0; mt < 2; ++mt)
#pragma unroll
        for (int nt = 0; nt < 4; ++nt) {
            const int t0 = 32 * w + 16 * mt + 4 * g;
            const int h  = 16 * nt + l15;
#pragma unroll
            for (int r = 0; r < 4; ++r) {
                smem[QS_OFF + (t0 + r) * QK_STR + h] = (bf16_t)accq[mt][nt][r];
                smem[KS_OFF + (t0 + r) * QK_STR + h] = (bf16_t)acck[mt][nt][r];
                smem[VT_OFF + h * VT_STR + t0 + r]   = (bf16_t)accv[mt][nt][r];
            }
        }
    __syncthreads();  // sync #1: qkv visible to all waves

    // ================= Phase 2: S = q k^T (skip fully-masked causal tiles) =================
    floatx4 sacc[2][8];
#pragma unroll
    for (int mt = 0; mt < 2; ++mt)
#pragma unroll
        for (int nt = 0; nt < 8; ++nt) sacc[mt][nt] = (floatx4)0.0f;

#pragma unroll
    for (int kt = 0; kt < 2; ++kt) {  // K = 64 -> 2 steps
        const int hh = 32 * kt + 8 * g;
        bf16x8 aq[2];
        aq[0] = *(const bf16x8*)(smem + QS_OFF + (32 * w + l15) * QK_STR + hh);
        aq[1] = *(const bf16x8*)(smem + QS_OFF + (32 * w + 16 + l15) * QK_STR + hh);
#pragma unroll
        for (int nt = 0; nt < 8; ++nt) {
            if (16 * nt <= 32 * w + 31) {  // wave-uniform: tile touches s <= t somewhere
                bf16x8 bk = *(const bf16x8*)(smem + KS_OFF + (16 * nt + l15) * QK_STR + hh);
                if (16 * nt <= 32 * w + 15) sacc[0][nt] = MFMA16(aq[0], bk, sacc[0][nt]);
                sacc[1][nt] = MFMA16(aq[1], bk, sacc[1][nt]);
            }
        }
    }
    __syncthreads();  // sync #2: everyone done reading q/k before P overlays them

    // ================= causal mask + softmax, P -> LDS bf16 =================
    const float scale = 0.05103103630798287f;  // 384^-0.5
#pragma unroll
    for (int mt = 0; mt < 2; ++mt) {
#pragma unroll
        for (int r = 0; r < 4; ++r) {
            const int t = 32 * w + 16 * mt + 4 * g + r;
            float vals[8];
            float vmax = -__builtin_inff();
#pragma unroll
            for (int nt = 0; nt < 8; ++nt) {
                const int s = 16 * nt + l15;
                float v = (s <= t) ? sacc[mt][nt][r] * scale : -__builtin_inff();
                vals[nt] = v;
                vmax = fmaxf(vmax, v);
            }
            vmax = fmaxf(vmax, __shfl_xor(vmax, 1));
            vmax = fmaxf(vmax, __shfl_xor(vmax, 2));
            vmax = fmaxf(vmax, __shfl_xor(vmax, 4));
            vmax = fmaxf(vmax, __shfl_xor(vmax, 8));
            float sum = 0.0f;
#pragma unroll
            for (int nt = 0; nt < 8; ++nt) {
                float e = __expf(vals[nt] - vmax);
                vals[nt] = e;
                sum += e;
            }
            sum += __shfl_xor(sum, 1);
            sum += __shfl_xor(sum, 2);
            sum += __shfl_xor(sum, 4);
            sum += __shfl_xor(sum, 8);
            const float inv = 1.0f / sum;
#pragma unroll
            for (int nt = 0; nt < 8; ++nt)
                smem[PS_OFF + t * VT_STR + 16 * nt + l15] = (bf16_t)(vals[nt] * inv);
        }
    }
    // no sync needed: each wave only reads back its own P rows

    // ================= O = P v (skip all-zero s-chunks past the causal edge) =================
    floatx4 oacc[2][4];
#pragma unroll
    for (int mt = 0; mt < 2; ++mt)
#pragma unroll
        for (int nt = 0; nt < 4; ++nt) oacc[mt][nt] = (floatx4)0.0f;

    for (int st = 0; st <= w; ++st) {  // s-chunks of 32; wave w needs s < 32(w+1)
        const int ss = 32 * st + 8 * g;
        bf16x8 ap0 = *(const bf16x8*)(smem + PS_OFF + (32 * w + l15) * VT_STR + ss);
        bf16x8 ap1 = *(const bf16x8*)(smem + PS_OFF + (32 * w + 16 + l15) * VT_STR + ss);
#pragma unroll
        for (int nt = 0; nt < 4; ++nt) {
            bf16x8 bv = *(const bf16x8*)(smem + VT_OFF + (16 * nt + l15) * VT_STR + ss);
            oacc[0][nt] = MFMA16(ap0, bv, oacc[0][nt]);
            oacc[1][nt] = MFMA16(ap1, bv, oacc[1][nt]);
        }
    }

    float* ob = out + (size_t)b * TT * HS;
#pragma unroll
    for (int mt = 0; mt < 2; ++mt)
#pragma unroll
        for (int nt = 0; nt < 4; ++nt) {
            const int t0 = 32 * w + 16 * mt + 4 * g;
            const int h  = 16 * nt + l15;
#pragma unroll
            for (int r = 0; r < 4; ++r)
                ob[(size_t)(t0 + r) * HS + h] = oacc[mt][nt][r];
        }
}

extern "C" void kernel_launch(void* const* d_in, const int* in_sizes, int n_in,
                              void* d_out, int out_size, void* d_ws, size_t ws_size,
                              hipStream_t stream) {
    // setup_inputs order: x, Wk, Wq, Wv
    const float* x  = (const float*)d_in[0];
    const float* wk = (const float*)d_in[1];
    const float* wq = (const float*)d_in[2];
    const float* wv = (const float*)d_in[3];
    float* out = (float*)d_out;

    bf16_t* wf = (bf16_t*)d_ws;  // fragment-ordered weights: 3*12*4*64*8 bf16 = 288 KB

    wconv_kernel<<<36, 256, 0, stream>>>(wq, wk, wv, wf);
    attn_kernel<<<BB, 256, 0, stream>>>(x, wf, out);
}

// Round 4
// 307.517 us; speedup vs baseline: 1.3339x; 1.0706x over previous
//
#include <hip/hip_runtime.h>

typedef __bf16 bf16_t;
typedef __attribute__((ext_vector_type(8))) __bf16 bf16x8;
typedef __attribute__((ext_vector_type(4))) float floatx4;

#define MFMA16(a, b, c) __builtin_amdgcn_mfma_f32_16x16x32_bf16((a), (b), (c), 0, 0, 0)
// async global->LDS, 16B/lane: lane i's 16B lands at ldsbase + i*16 (wave-uniform base)
#define GLOAD_LDS(g, l)                                                                      \
    __builtin_amdgcn_global_load_lds((const __attribute__((address_space(1))) unsigned int*)(g), \
                                     (__attribute__((address_space(3))) unsigned int*)(l), 16, 0, 0)

constexpr int TT = 128;   // sequence length
constexpr int CD = 384;   // n_emb
constexpr int HS = 64;    // head size
constexpr int BB = 1024;  // batch
constexpr int NCH = 12;   // K chunks of 32

// ---- phase-1 LDS byte layout (double-buffered) ----
// x chunk: 128 rows x 32 fp32 cols, staggered: pair p (rows 2p,2p+1) at [p*272, p*272+256), 16B pad
//   -> row r at (r>>1)*272 + (r&1)*128; 64 pairs * 272 = 17408 B = 17 staging instrs exactly
// w chunk: 12 frags (3 proj x 4 nt) x 1024 B, chunk-major from wconv
constexpr int XB0 = 0, XB1 = 17408, WB0 = 34816, WB1 = 47104;
constexpr int SMEM_BYTES = 59392;  // 59.4 KB -> 2 blocks/CU

// ---- phase-2 overlay (bf16 elements), same as round 3 (54272 B <= 59392) ----
constexpr int QK_STR = 72;
constexpr int VT_STR = 136;
constexpr int QS_OFF = 0;
constexpr int KS_OFF = TT * QK_STR;
constexpr int VT_OFF = 2 * TT * QK_STR;
constexpr int PS_OFF = 0;

// ---- pre-kernel: weights -> bf16 fragments in CHUNK-MAJOR order ----
// frag f = (kki*3 + proj)*4 + nt ; wf[f*512 + lane*8 + j] = W_proj[16nt + (lane&15)][32kki + 8(lane>>4) + j]
__global__ void wconv_kernel(const float* __restrict__ wq, const float* __restrict__ wk,
                             const float* __restrict__ wv, bf16_t* __restrict__ wf) {
    const int t = blockIdx.x * 256 + threadIdx.x;
    if (t >= 144 * 64) return;
    const int lane = t & 63;
    const int f    = t >> 6;
    const int nt   = f & 3;
    const int proj = (f >> 2) % 3;
    const int kki  = f / 12;
    const float* W = (proj == 0) ? wq : ((proj == 1) ? wk : wv);
    const int h = 16 * nt + (lane & 15);
    const int c = 32 * kki + 8 * (lane >> 4);
    const float* src = W + h * CD + c;
    bf16x8 o;
#pragma unroll
    for (int j = 0; j < 8; ++j) o[j] = (bf16_t)src[j];
    *(bf16x8*)(wf + (size_t)t * 8) = o;
}

// ---- fused attention head: 1 block/batch, 4 waves, async-staged m97-style phase 1 ----
__launch_bounds__(256, 2)
__global__ void attn_kernel(const float* __restrict__ x, const bf16_t* __restrict__ wf,
                            float* __restrict__ out) {
    __shared__ __align__(16) char smem_raw[SMEM_BYTES];
    bf16_t* smem = (bf16_t*)smem_raw;
    const int b    = blockIdx.x;
    const int lane = threadIdx.x & 63;
    const int w    = threadIdx.x >> 6;
    const int l15  = lane & 15;
    const int g    = lane >> 4;
    const char* xb  = (const char*)(x + (size_t)b * TT * CD);
    const char* wfb = (const char*)wf;

    // ---- per-lane x-staging map (computed once): instr i covers LDS bytes [i*1024,(i+1)*1024) ----
    // LDS byte u -> pair u/272; rem<256: row = 2p + (rem>>7), col byte = rem&127; else pad lane
    int      xi[5];
    unsigned xg[5];
#pragma unroll
    for (int t2 = 0; t2 < 5; ++t2) {
        const int i = w + 4 * t2;  // wave 0: 0,4,8,12,16 ; waves 1-3: 4 instrs
        xi[t2] = i;
        unsigned u   = (unsigned)i * 1024u + (unsigned)lane * 16u;
        unsigned p   = u / 272u;
        unsigned rem = u - 272u * p;
        unsigned row = 2u * p + (rem >> 7);
        xg[t2] = (rem < 256u) ? row * (CD * 4u) + (rem & 127u) : 0u;  // pad lanes read row 0 (harmless)
    }

    auto stage = [&](int c) {
        const char* xsrc = xb + c * 128;  // this chunk's 32 cols = 128 B within each row
        char*       xd   = smem_raw + ((c & 1) ? XB1 : XB0);
#pragma unroll
        for (int t2 = 0; t2 < 5; ++t2)
            if (xi[t2] <= 16) GLOAD_LDS(xsrc + xg[t2], xd + xi[t2] * 1024);
        const char* wsrc = wfb + (size_t)(c * 12 + 3 * w) * 1024 + (size_t)lane * 16;
        char*       wd   = smem_raw + ((c & 1) ? WB1 : WB0) + 3 * w * 1024;
#pragma unroll
        for (int j = 0; j < 3; ++j) GLOAD_LDS(wsrc + (size_t)j * 1024, wd + j * 1024);
    };

    // ================= Phase 1: q,k,v projections =================
    floatx4 accq[2][4], acck[2][4], accv[2][4];
#pragma unroll
    for (int mt = 0; mt < 2; ++mt)
#pragma unroll
        for (int nt = 0; nt < 4; ++nt) {
            accq[mt][nt] = (floatx4)0.0f;
            acck[mt][nt] = (floatx4)0.0f;
            accv[mt][nt] = (floatx4)0.0f;
        }

    stage(0);
    __syncthreads();  // chunk 0 resident

    for (int c = 0; c < NCH; ++c) {
        if (c + 1 < NCH) stage(c + 1);  // async into the other buffer; completes by next barrier

        const char*   xs = smem_raw + ((c & 1) ? XB1 : XB0);
        const char*   ws = smem_raw + ((c & 1) ? WB1 : WB0);

        bf16x8 a[2];
#pragma unroll
        for (int mt = 0; mt < 2; ++mt) {
            const int   R = 32 * w + 16 * mt + l15;
            const char* p = xs + (R >> 1) * 272 + (R & 1) * 128 + 32 * g;
            float4 f0 = *(const float4*)p;
            float4 f1 = *(const float4*)(p + 16);
            bf16x8 t;
            t[0] = (bf16_t)f0.x; t[1] = (bf16_t)f0.y; t[2] = (bf16_t)f0.z; t[3] = (bf16_t)f0.w;
            t[4] = (bf16_t)f1.x; t[5] = (bf16_t)f1.y; t[6] = (bf16_t)f1.z; t[7] = (bf16_t)f1.w;
            a[mt] = t;
        }
        bf16x8 wbf[12];
#pragma unroll
        for (int pn = 0; pn < 12; ++pn)
            wbf[pn] = *(const bf16x8*)(ws + pn * 1024 + lane * 16);
#pragma unroll
        for (int nt = 0; nt < 4; ++nt) {
            accq[0][nt] = MFMA16(a[0], wbf[0 + nt], accq[0][nt]);
            accq[1][nt] = MFMA16(a[1], wbf[0 + nt], accq[1][nt]);
            acck[0][nt] = MFMA16(a[0], wbf[4 + nt], acck[0][nt]);
            acck[1][nt] = MFMA16(a[1], wbf[4 + nt], acck[1][nt]);
            accv[0][nt] = MFMA16(a[0], wbf[8 + nt], accv[0][nt]);
            accv[1][nt] = MFMA16(a[1], wbf[8 + nt], accv[1][nt]);
        }
        __syncthreads();  // chunk c fully consumed by all waves; chunk c+1 staging drained
    }

    // ---- write q,k as [t][h], v transposed as [h][t] into the (now dead) phase-1 area ----
#pragma unroll
    for (int mt = 0; mt < 2; ++mt)
#pragma unroll
        for (int nt = 0; nt < 4; ++nt) {
            const int t0 = 32 * w + 16 * mt + 4 * g;
            const int h  = 16 * nt + l15;
#pragma unroll
            for (int r = 0; r < 4; ++r) {
                smem[QS_OFF + (t0 + r) * QK_STR + h] = (bf16_t)accq[mt][nt][r];
                smem[KS_OFF + (t0 + r) * QK_STR + h] = (bf16_t)acck[mt][nt][r];
                smem[VT_OFF + h * VT_STR + t0 + r]   = (bf16_t)accv[mt][nt][r];
            }
        }
    __syncthreads();  // qkv visible to all waves

    // ================= Phase 2: S = q k^T (skip fully-masked causal tiles) =================
    floatx4 sacc[2][8];
#pragma unroll
    for (int mt = 0; mt < 2; ++mt)
#pragma unroll
        for (int nt = 0; nt < 8; ++nt) sacc[mt][nt] = (floatx4)0.0f;

#pragma unroll
    for (int kt = 0; kt < 2; ++kt) {
        const int hh = 32 * kt + 8 * g;
        bf16x8 aq[2];
        aq[0] = *(const bf16x8*)(smem + QS_OFF + (32 * w + l15) * QK_STR + hh);
        aq[1] = *(const bf16x8*)(smem + QS_OFF + (32 * w + 16 + l15) * QK_STR + hh);
#pragma unroll
        for (int nt = 0; nt < 8; ++nt) {
            if (16 * nt <= 32 * w + 31) {
                bf16x8 bk = *(const bf16x8*)(smem + KS_OFF + (16 * nt + l15) * QK_STR + hh);
                if (16 * nt <= 32 * w + 15) sacc[0][nt] = MFMA16(aq[0], bk, sacc[0][nt]);
                sacc[1][nt] = MFMA16(aq[1], bk, sacc[1][nt]);
            }
        }
    }
    __syncthreads();  // q/k reads done before P overlays them

    // ================= causal mask + softmax, P -> LDS bf16 =================
    const float scale = 0.05103103630798287f;  // 384^-0.5
#pragma unroll
    for (int mt = 0; mt < 2; ++mt) {
#pragma unroll
        for (int r = 0; r < 4; ++r) {
            const int t = 32 * w + 16 * mt + 4 * g + r;
            float vals[8];
            float vmax = -__builtin_inff();
#pragma unroll
            for (int nt = 0; nt < 8; ++nt) {
                const int s = 16 * nt + l15;
                float v = (s <= t) ? sacc[mt][nt][r] * scale : -__builtin_inff();
                vals[nt] = v;
                vmax = fmaxf(vmax, v);
            }
            vmax = fmaxf(vmax, __shfl_xor(vmax, 1));
            vmax = fmaxf(vmax, __shfl_xor(vmax, 2));
            vmax = fmaxf(vmax, __shfl_xor(vmax, 4));
            vmax = fmaxf(vmax, __shfl_xor(vmax, 8));
            float sum = 0.0f;
#pragma unroll
            for (int nt = 0; nt < 8; ++nt) {
                float e = __expf(vals[nt] - vmax);
                vals[nt] = e;
                sum += e;
            }
            sum += __shfl_xor(sum, 1);
            sum += __shfl_xor(sum, 2);
            sum += __shfl_xor(sum, 4);
            sum += __shfl_xor(sum, 8);
            const float inv = 1.0f / sum;
#pragma unroll
            for (int nt = 0; nt < 8; ++nt)
                smem[PS_OFF + t * VT_STR + 16 * nt + l15] = (bf16_t)(vals[nt] * inv);
        }
    }
    // no sync: each wave reads back only its own P rows

    // ================= O = P v (skip all-zero s-chunks past the causal edge) =================
    floatx4 oacc[2][4];
#pragma unroll
    for (int mt = 0; mt < 2; ++mt)
#pragma unroll
        for (int nt = 0; nt < 4; ++nt) oacc[mt][nt] = (floatx4)0.0f;

    for (int st = 0; st <= w; ++st) {
        const int ss = 32 * st + 8 * g;
        bf16x8 ap0 = *(const bf16x8*)(smem + PS_OFF + (32 * w + l15) * VT_STR + ss);
        bf16x8 ap1 = *(const bf16x8*)(smem + PS_OFF + (32 * w + 16 + l15) * VT_STR + ss);
#pragma unroll
        for (int nt = 0; nt < 4; ++nt) {
            bf16x8 bv = *(const bf16x8*)(smem + VT_OFF + (16 * nt + l15) * VT_STR + ss);
            oacc[0][nt] = MFMA16(ap0, bv, oacc[0][nt]);
            oacc[1][nt] = MFMA16(ap1, bv, oacc[1][nt]);
        }
    }

    float* ob = out + (size_t)b * TT * HS;
#pragma unroll
    for (int mt = 0; mt < 2; ++mt)
#pragma unroll
        for (int nt = 0; nt < 4; ++nt) {
            const int t0 = 32 * w + 16 * mt + 4 * g;
            const int h  = 16 * nt + l15;
#pragma unroll
            for (int r = 0; r < 4; ++r)
                ob[(size_t)(t0 + r) * HS + h] = oacc[mt][nt][r];
        }
}

extern "C" void kernel_launch(void* const* d_in, const int* in_sizes, int n_in,
                              void* d_out, int out_size, void* d_ws, size_t ws_size,
                              hipStream_t stream) {
    // setup_inputs order: x, Wk, Wq, Wv
    const float* x  = (const float*)d_in[0];
    const float* wk = (const float*)d_in[1];
    const float* wq = (const float*)d_in[2];
    const float* wv = (const float*)d_in[3];
    float* out = (float*)d_out;

    bf16_t* wf = (bf16_t*)d_ws;  // chunk-major weight fragments: 144 KB

    wconv_kernel<<<36, 256, 0, stream>>>(wq, wk, wv, wf);
    attn_kernel<<<BB, 256, 0, stream>>>(x, wf, out);
}